// Round 7
// baseline (83.420 us; speedup 1.0000x reference)
//
#include <hip/hip_runtime.h>

#define EPS_F 1e-7f
#define NN 32        // N fixed at 32 by the problem setup
#define MARGIN 3     // conservative range margin (anchor units); fp slop ≤ 0.05
#define NSEG (NN * 6)
#define TPB 256      // 4 waves/block; 32 blocks -> 32 CUs
#define SLICES 8     // candidate-space slices per sample
#define CHUNK 4      // software-pipeline factor for the candidate loop
#define CAND_MAX 24576  // provable worst-case T ~19k + slack
#define CNT_OFF 4096    // byte offset of per-sample counters in ws

// rl_sliced v7: grid (SLICES, B) = 32 blocks, ordinary launch (NO
// cooperative kernel — v5 showed +35 µs under graph capture).
// v6 (12.4 µs exec) ran everything on 4 CUs; the residual was per-CU
// serial latency (cold icache/TLB after the 256 MiB poison fill, setup
// phases, one long chunk chain) that more CUs can parallelize. v7:
//   - setup (sort/ranges/segmask/scan/cand map) replicated per block,
//     parallel across 32 CUs (~1.5 µs, not worth a cross-block handoff)
//   - each block covers 1/SLICES of the flat candidate space (~2
//     candidates/thread -> one CHUNK=4 pipelined iteration)
//   - finish: atomic last-block pattern. Slot write via atomicExch,
//     __threadfence, per-sample counter atomicAdd; the last block reads
//     the SLICES slots in FIXED order (coherent atomicAdd(p,0)) and
//     writes out[b] -> bit-deterministic. Counter zeroed each iteration
//     by an 8 KiB hipMemsetAsync before the kernel (graph-capturable;
//     the harness's own reset enqueues dozens of such tiny memsets).
// Candidate enumeration, exact fp32 predicate, overlap-mask first-match
// and rcp-GIoU are byte-identical to v6/v4 (absmax 0.0).
__global__ __launch_bounds__(TPB) void rl_sliced(
    const float* __restrict__ reg,   // (B, A, 2)
    const float* __restrict__ ann,   // (B, N, 3)
    int c0, int A,
    float* __restrict__ ws,          // slots + counters (see layout above)
    float* __restrict__ out)         // (B,) final loss per sample
{
    const int s_blk = blockIdx.x;
    const int b = blockIdx.y;
    const int t = threadIdx.x;
    const int wave = t >> 6;
    const int lane = t & 63;

    __shared__ float2 sh_se[NN];       // sorted (s,e), ascending length
    __shared__ int4   seg[NSEG];       // {l0, r0, lenL|(lenR<<16), start<<16|n<<8|lvl}
    __shared__ int    pfx[NSEG];       // counts, then inclusive prefix
    __shared__ unsigned segmask[NSEG]; // earlier-gt overlap mask per segment
    __shared__ unsigned cand32[CAND_MAX / 4];  // flat candidate -> segment id
    __shared__ float  sh_sz[8];
    __shared__ float  red_l[TPB / 64], red_p[TPB / 64];

    // SIZES as double-exprs cast to f32 — JAX weak-scalar promotion.
    if (t < 8) {
        const float szc[8] = {
            0.0f,
            (float)(2.23147392 * (22050.0 / 256.0)),
            (float)(2.62519274 * (22050.0 / 256.0)),
            (float)(3.74199546 * (22050.0 / 256.0)),
            (float)(5.78800454 * (22050.0 / 256.0)),
            (float)(8.02371882 * (22050.0 / 256.0)),
            __builtin_inff(), __builtin_inff()
        };
        sh_sz[t] = szc[t];
    }

    // Shfl-based stable rank sort by length (wave 0, lanes 0..31 only) —
    // identical to the verified kernel.
    if (t < NN) {
        const float* an = ann + (size_t)b * (size_t)NN * 3;
        const float s0 = an[t * 3 + 0];
        const float e0 = an[t * 3 + 1];
        const float len = e0 - s0;
        int rank = 0;
#pragma unroll
        for (int j = 0; j < NN; ++j) {
            const float lj = __shfl(len, j, 64);
            rank += (lj < len) || (lj == len && j < t);
        }
        sh_se[rank] = make_float2(s0, e0);
    }
    __syncthreads();

    // Every lane caches sorted gt (s,e) for lane&31 -> 2 VGPR; the segmask
    // overlap test reads it via __shfl (VALU, no LDS latency).
    float tsx, tsy;
    {
        const float2 tmp = sh_se[lane & 31];
        tsx = tmp.x; tsy = tmp.y;
    }

    // Per-(gt,lvl) conservative ranges — verified MARGIN superset logic —
    // plus the earlier-gt overlap mask. t<192 = waves 0..2 fully active.
    if (t < NSEG) {
        const int n   = t / 6;
        const int lvl = t - n * 6;
        const float2 se = sh_se[n];
        const float s = se.x, e = se.y;
        const float mid   = 0.5f * (s + e);
        const float halfL = 0.5f * (e - s);
        const float lo = sh_sz[lvl];
        const float hi = sh_sz[lvl + 1];
        const int   cnt = c0 >> lvl;
        const float inv   = __int_as_float((127 - lvl) << 23);  // 2^-lvl
        const float scale = __int_as_float((127 + lvl) << 23);  // 2^lvl

        // m(pt) = L/2 + |pt - mid|; band => |pt-mid| in [dlo, dhi).
        const float dlo = fmaxf(lo - halfL, 0.0f);
        const float dhi = hi - halfL;                // +inf at lvl 5 is fine
        const float prl = fmaxf(mid + dlo, s);       // right interval
        const float prh = fminf(mid + dhi, e);
        const float pll = fmaxf(mid - dhi, s);       // left interval
        const float plh = fminf(mid - dlo, e);

        int r0 = (int)floorf(prl * inv - 0.5f) - MARGIN;
        int r1 = (int)floorf(prh * inv - 0.5f) + MARGIN;
        int l0 = (int)floorf(pll * inv - 0.5f) - MARGIN;
        int l1 = (int)floorf(plh * inv - 0.5f) + MARGIN;
        r0 = max(r0, 0); r1 = min(r1, cnt - 1);
        l0 = max(l0, 0); l1 = min(l1, cnt - 1);
        if (r1 >= r0) l1 = min(l1, r0 - 1);          // disjoint union
        const int lenL = max(l1 - l0 + 1, 0);
        const int lenR = max(r1 - r0 + 1, 0);
        seg[t] = make_int4(l0, r0, lenL | (lenR << 16), (n << 8) | lvl);
        pfx[t] = lenL + lenR;

        // Anchor-pt span of this segment (same fp expr as the j-loop's pt,
        // so the span test is an exact superset of the in_gt condition).
        const int firstloc = lenL ? l0 : r0;
        const int lastloc  = lenR ? r1 : l1;
        const float ptmin = ((float)firstloc + 0.5f) * scale;
        const float ptmax = ((float)lastloc  + 0.5f) * scale;
        unsigned msk = 0u;
#pragma unroll
        for (int n2 = 0; n2 < NN - 1; ++n2) {
            const float ox = __shfl(tsx, n2, 64);    // uniform: waves 0-2 full
            const float oy = __shfl(tsy, n2, 64);
            msk |= ((n2 < n) & (ox <= ptmax) & (oy >= ptmin)) ? (1u << n2) : 0u;
        }
        segmask[t] = msk;
    }
    __syncthreads();

    // Wave-0 shfl inclusive scan over the 192 counts (3 chunks of 64).
    if (wave == 0) {
        int carry = 0;
#pragma unroll
        for (int k = 0; k < 3; ++k) {
            int v = pfx[k * 64 + lane];
#pragma unroll
            for (int o = 1; o < 64; o <<= 1) {
                const int u = __shfl_up(v, o, 64);
                v += (lane >= o) ? u : 0;
            }
            pfx[k * 64 + lane] = v + carry;
            carry += __shfl(v, 63, 64);   // chunk total, broadcast
        }
    }
    __syncthreads();
    const int T = min(pfx[NSEG - 1], CAND_MAX);   // clamp provably inactive

    // Fill the flat candidate->segment byte map (u32-packed); pack start
    // into seg.w high 16 bits (start < 24576 < 2^16).
    if (t < NSEG) {
        const int4 sg = seg[t];
        const int count = (sg.z & 0xffff) + (sg.z >> 16);
        const int start = pfx[t] - count;
        seg[t].w = sg.w | (start << 16);
        unsigned char* cbw = (unsigned char*)cand32;
        int i = start;
        const int end = min(start + count, CAND_MAX);
        const unsigned rep = 0x01010101u * (unsigned)t;
        while (i < end && (i & 3)) cbw[i++] = (unsigned char)t;
        for (; i + 4 <= end; i += 4) cand32[i >> 2] = rep;
        for (; i < end; ++i) cbw[i] = (unsigned char)t;
    }
    __syncthreads();

    const int twoc0 = 2 * c0;
    const unsigned char* cb = (const unsigned char*)cand32;
    const float2* reg2 = (const float2*)reg + (size_t)b * A;
    float loss_sum = 0.0f, pos_sum = 0.0f;

    for (int jb = s_blk * TPB + t; jb < T; jb += SLICES * TPB * CHUNK) {
        // ---- phase 1: decode + issue all CHUNK independent load chains ----
        float2 gk[CHUNK];
        float  ptk[CHUNK], lk[CHUNK], rk[CHUNK], lok[CHUNK], hik[CHUNK], invk[CHUNK];
        unsigned mskk[CHUNK];
        bool validk[CHUNK];
#pragma unroll
        for (int k = 0; k < CHUNK; ++k) {
            const int j = jb + k * (SLICES * TPB);
            const bool act = j < T;
            const int jj = act ? j : 0;              // clamp to a real candidate
            const int sid = cb[jj];                  // 1 LDS byte read
            const int4 sg = seg[sid];                // 1 ds_read_b128
            mskk[k] = segmask[sid];                  // independent b32 read
            const int lenL  = sg.z & 0xffff;
            const int start = (int)(((unsigned)sg.w) >> 16);
            const int n     = (sg.w >> 8) & 0xff;
            const int lvl   = sg.w & 0xff;
            const int local = jj - start;
            const int loc = (local < lenL) ? (sg.x + local) : (sg.y + (local - lenL));
            const float scale = __int_as_float((127 + lvl) << 23);  // 2^lvl
            invk[k] = __int_as_float((127 - lvl) << 23);            // 2^-lvl
            const int aoff = twoc0 - (twoc0 >> lvl);

            // Global load issued here — independent across k, all in flight.
            gk[k] = reg2[aoff + loc];

            const float pt = ((float)loc + 0.5f) * scale;  // bit-exact anchor
            ptk[k] = pt;
            lok[k] = sh_sz[lvl];
            hik[k] = sh_sz[lvl + 1];
            const float2 se = sh_se[n];
            const float l = pt - se.x;
            const float r = se.y - pt;
            lk[k] = l; rk[k] = r;
            const float m = fmaxf(l, r);
            // EXACT reference predicate (fp32, same op order/compares).
            validk[k] = act & (fminf(l, r) >= 0.0f) & (m >= lok[k]) & (m < hik[k]);
        }

        // ---- phase 2: first-match + GIoU from registers ----
#pragma unroll
        for (int k = 0; k < CHUNK; ++k) {
            bool valid = validk[k];
            unsigned msk = mskk[k];
            const float pt = ptk[k];
            const float lo = lok[k], hi = hik[k];
            // First-match via overlap mask: exact predicate only on the
            // (rare) earlier gts whose [s,e] intersects the anchor span.
            while (valid && msk) {
                const int n2 = __builtin_ctz(msk);
                msk &= msk - 1u;
                const float2 o = sh_se[n2];
                const float l2 = pt - o.x;
                const float r2 = o.y - pt;
                const float m2 = fmaxf(l2, r2);
                if ((fminf(l2, r2) >= 0.0f) & (m2 >= lo) & (m2 < hi)) valid = false;
            }

            // GIoU epilogue (rcp; validated absmax 0 vs 3.9e-2 threshold).
            const float inv = invk[k];
            const float2 g = gk[k];
            const float b0 = pt - lk[k] * inv;
            const float b1 = pt + rk[k] * inv;
            const float inter = fmaxf(fminf(b1, g.y) - fmaxf(b0, g.x), 0.0f);
            const float uni = (b1 - b0) + (g.y - g.x) - inter;
            const float iou = inter * __builtin_amdgcn_rcpf(uni + EPS_F);
            const float enc = fmaxf(b1, g.y) - fminf(b0, g.x);
            float giou = iou - (enc - uni) * __builtin_amdgcn_rcpf(enc + EPS_F);
            giou = fminf(fmaxf(giou, -1.0f), 1.0f);
            loss_sum += valid ? (1.0f - giou) : 0.0f;
            pos_sum  += valid ? 1.0f : 0.0f;
        }
    }

    // In-block reduction: wave shfl + LDS cross-wave.
    for (int o = 32; o > 0; o >>= 1) {
        loss_sum += __shfl_down(loss_sum, o, 64);
        pos_sum  += __shfl_down(pos_sum,  o, 64);
    }
    if (lane == 0) { red_l[wave] = loss_sum; red_p[wave] = pos_sum; }
    __syncthreads();

    // Atomic last-block finish (device-scope; coherent across XCDs).
    if (t == 0) {
        float Ls = 0.0f, Ps = 0.0f;
#pragma unroll
        for (int w = 0; w < TPB / 64; ++w) { Ls += red_l[w]; Ps += red_p[w]; }
        float* slot = ws + ((size_t)b * SLICES + s_blk) * 2;
        atomicExch(&slot[0], Ls);
        atomicExch(&slot[1], Ps);
        __threadfence();
        unsigned* cnt = (unsigned*)((char*)ws + CNT_OFF + (size_t)b * 64);
        const unsigned old = atomicAdd(cnt, 1u);
        if (old == SLICES - 1) {          // last block of sample b
            __threadfence();
            float Lt = 0.0f, Pt = 0.0f;
#pragma unroll
            for (int i = 0; i < SLICES; ++i) {    // fixed order: deterministic
                float* sl = ws + ((size_t)b * SLICES + i) * 2;
                Lt += atomicAdd(&sl[0], 0.0f);    // coherent read
                Pt += atomicAdd(&sl[1], 0.0f);
            }
            out[b] = Lt / fmaxf(Pt, 1.0f);
        }
    }
}

extern "C" void kernel_launch(void* const* d_in, const int* in_sizes, int n_in,
                              void* d_out, int out_size, void* d_ws, size_t ws_size,
                              hipStream_t stream) {
    const float* reg = (const float*)d_in[0];
    const float* ann = (const float*)d_in[1];
    // d_in[2] = class_id (unused); anchors d_in[3..8] are analytic, not read.
    const int c0 = in_sizes[3];
    const int A = in_sizes[3] + in_sizes[4] + in_sizes[5] +
                  in_sizes[6] + in_sizes[7] + in_sizes[8];
    const int B = out_size;                  // 4

    // Zero the slot+counter region (first 8 KiB of ws) each iteration;
    // stream-ordered after the harness's poison fill, graph-capturable.
    hipMemsetAsync(d_ws, 0, 8192, stream);
    rl_sliced<<<dim3(SLICES, B), TPB, 0, stream>>>(
        reg, ann, c0, A, (float*)d_ws, (float*)d_out);
}

// Round 8
// 77.175 us; speedup vs baseline: 1.0809x; 1.0809x over previous
//
#include <hip/hip_runtime.h>

#define EPS_F 1e-7f
#define NN 32        // N fixed at 32 by the problem setup
#define MARGIN 3     // conservative range margin (anchor units); fp slop ≤ 0.05
#define TPB 1024     // 16 waves; 32 threads per gt
#define CHUNK 2      // software-pipeline factor (keeps VGPR <= 128 at 1024 thr)

// rl_lean v8: same verified candidate set / fp semantics as v6 (best, 74.0),
// but with the setup machinery deleted. v6 spent its unexplained ~8 µs on
// per-dispatch serial overhead: 7 barriers x 16 waves, multi-phase setup
// (scan + LDS candidate map + serial map fill), ~8 KB unrolled code on a
// cold icache, and a 2-deep LDS decode chain per candidate. v8:
//   - gt n = t>>5 owned by 32 threads; each thread recomputes its gt's 6
//     level ranges IN REGISTERS (identical verified math, parallel, no
//     scan, no map, no fill)
//   - candidate -> (lvl,loc) decode is a 5-step in-register select chain
//     (zero LDS on the decode path)
//   - per-gt overlap mask (earlier gts with [s2,e2] ∩ [s,e] != 0): valid
//     candidates lie in [s,e], so this is a superset of v6's per-segment
//     mask -> ctz loop still applies the EXACT predicate per bit
//   - 3 barriers total; LDS < 1 KB; code ~half of v6
// Exact fp32 predicate, first-match semantics, and rcp-GIoU byte-identical
// to v6 (absmax 0.0 expected; only summation order differs).
// NO cooperative launch (v5), NO extra graph nodes / cross-block traffic (v7).
__global__ __launch_bounds__(TPB) void rl_lean(
    const float* __restrict__ reg,   // (B, A, 2)
    const float* __restrict__ ann,   // (B, N, 3)
    int c0, int A,
    float* __restrict__ out)         // (B,) final loss per sample
{
    const int b = blockIdx.x;
    const int t = threadIdx.x;
    const int wave = t >> 6;
    const int lane = t & 63;
    const int n    = t >> 5;         // owning gt (0..31)
    const int slot = t & 31;         // lane within the gt's thread group

    __shared__ float2 sh_se[NN];     // sorted (s,e), ascending length
    __shared__ float  sh_sz[8];
    __shared__ float  red_l[TPB / 64], red_p[TPB / 64];

    // SIZES as double-exprs cast to f32 — JAX weak-scalar promotion.
    if (t < 8) {
        const float szc[8] = {
            0.0f,
            (float)(2.23147392 * (22050.0 / 256.0)),
            (float)(2.62519274 * (22050.0 / 256.0)),
            (float)(3.74199546 * (22050.0 / 256.0)),
            (float)(5.78800454 * (22050.0 / 256.0)),
            (float)(8.02371882 * (22050.0 / 256.0)),
            __builtin_inff(), __builtin_inff()
        };
        sh_sz[t] = szc[t];
    }

    // Shfl-based stable rank sort by length (wave 0, lanes 0..31 only) —
    // identical to the verified kernel.
    if (t < NN) {
        const float* an = ann + (size_t)b * (size_t)NN * 3;
        const float s0 = an[t * 3 + 0];
        const float e0 = an[t * 3 + 1];
        const float len = e0 - s0;
        int rank = 0;
#pragma unroll
        for (int j = 0; j < NN; ++j) {
            const float lj = __shfl(len, j, 64);
            rank += (lj < len) || (lj == len && j < t);
        }
        sh_se[rank] = make_float2(s0, e0);
    }
    __syncthreads();

    // Own gt interval + lane-cached table for the shfl overlap mask.
    const float2 myse = sh_se[n];
    const float s = myse.x, e = myse.y;
    float tsx, tsy;
    {
        const float2 tmp = sh_se[lane & 31];
        tsx = tmp.x; tsy = tmp.y;
    }

    // Per-gt earlier-overlap mask: n2 < n with [s2,e2] ∩ [s,e] nonempty.
    // Valid candidates satisfy pt ∈ [s,e], so any stealing gt must have
    // s2 <= e && e2 >= s -> superset of v6's per-segment mask. Unrolled
    // shfl loop: pure VALU, no LDS latency.
    unsigned msk_gt = 0u;
#pragma unroll
    for (int n2 = 0; n2 < NN - 1; ++n2) {
        const float ox = __shfl(tsx, n2, 64);
        const float oy = __shfl(tsy, n2, 64);
        msk_gt |= ((n2 < n) & (ox <= e) & (oy >= s)) ? (1u << n2) : 0u;
    }

    // Per-thread: this gt's 6 level ranges, in registers (verified MARGIN
    // superset logic, unrolled -> static indices only).
    const float mid   = 0.5f * (s + e);
    const float halfL = 0.5f * (e - s);
    int l0a[6], r0a[6], lenLa[6], cumi[6];
    {
        int run = 0;
#pragma unroll
        for (int lvl = 0; lvl < 6; ++lvl) {
            const float lo = sh_sz[lvl];
            const float hi = sh_sz[lvl + 1];
            const int   cnt = c0 >> lvl;
            const float inv = __int_as_float((127 - lvl) << 23);  // 2^-lvl

            // m(pt) = L/2 + |pt - mid|; band => |pt-mid| in [dlo, dhi).
            const float dlo = fmaxf(lo - halfL, 0.0f);
            const float dhi = hi - halfL;                // +inf at lvl 5 ok
            const float prl = fmaxf(mid + dlo, s);       // right interval
            const float prh = fminf(mid + dhi, e);
            const float pll = fmaxf(mid - dhi, s);       // left interval
            const float plh = fminf(mid - dlo, e);

            int r0 = (int)floorf(prl * inv - 0.5f) - MARGIN;
            int r1 = (int)floorf(prh * inv - 0.5f) + MARGIN;
            int l0 = (int)floorf(pll * inv - 0.5f) - MARGIN;
            int l1 = (int)floorf(plh * inv - 0.5f) + MARGIN;
            r0 = max(r0, 0); r1 = min(r1, cnt - 1);
            l0 = max(l0, 0); l1 = min(l1, cnt - 1);
            if (r1 >= r0) l1 = min(l1, r0 - 1);          // disjoint union
            const int lenL = max(l1 - l0 + 1, 0);
            const int lenR = max(r1 - r0 + 1, 0);
            l0a[lvl] = l0; r0a[lvl] = r0; lenLa[lvl] = lenL;
            run += lenL + lenR;
            cumi[lvl] = run;
        }
    }
    const int total = cumi[5];

    const int twoc0 = 2 * c0;
    const float2* reg2 = (const float2*)reg + (size_t)b * A;
    float loss_sum = 0.0f, pos_sum = 0.0f;

    for (int cb = slot; cb < total; cb += 32 * CHUNK) {
        // ---- phase 1: decode + issue CHUNK independent load chains ----
        float2 gk[CHUNK];
        float  ptk[CHUNK], lk[CHUNK], rk[CHUNK], lok[CHUNK], hik[CHUNK], invk[CHUNK];
        bool validk[CHUNK];
#pragma unroll
        for (int k = 0; k < CHUNK; ++k) {
            const int c = cb + k * 32;
            const bool act = c < total;
            const int cc = act ? c : cb;             // cb < total: valid clamp

            // In-register level decode: last lvl with cumi[lvl-1] <= cc.
            int base = 0, pl0 = l0a[0], pr0 = r0a[0], plenL = lenLa[0], plvl = 0;
#pragma unroll
            for (int L = 1; L < 6; ++L) {
                const bool sel = cc >= cumi[L - 1];
                base  = sel ? cumi[L - 1] : base;
                pl0   = sel ? l0a[L]   : pl0;
                pr0   = sel ? r0a[L]   : pr0;
                plenL = sel ? lenLa[L] : plenL;
                plvl  = sel ? L        : plvl;
            }
            const int local = cc - base;
            const int loc = (local < plenL) ? (pl0 + local)
                                            : (pr0 + (local - plenL));
            const float scale = __int_as_float((127 + plvl) << 23);  // 2^lvl
            invk[k] = __int_as_float((127 - plvl) << 23);            // 2^-lvl
            const int aoff = twoc0 - (twoc0 >> plvl);

            // Global load issued here — independent across k, in flight
            // under the rest of the decode + phase 2.
            gk[k] = reg2[aoff + loc];

            const float pt = ((float)loc + 0.5f) * scale;  // bit-exact anchor
            ptk[k] = pt;
            lok[k] = sh_sz[plvl];
            hik[k] = sh_sz[plvl + 1];
            const float l = pt - s;
            const float r = e - pt;
            lk[k] = l; rk[k] = r;
            const float m = fmaxf(l, r);
            // EXACT reference predicate (fp32, same op order/compares).
            validk[k] = act & (fminf(l, r) >= 0.0f) & (m >= lok[k]) & (m < hik[k]);
        }

        // ---- phase 2: first-match + GIoU from registers ----
#pragma unroll
        for (int k = 0; k < CHUNK; ++k) {
            bool valid = validk[k];
            unsigned msk = msk_gt;
            const float pt = ptk[k];
            const float lo = lok[k], hi = hik[k];
            // First-match: exact predicate only on the (rare) earlier gts
            // overlapping [s,e] (superset mask; bits usually 0).
            while (valid && msk) {
                const int n2 = __builtin_ctz(msk);
                msk &= msk - 1u;
                const float2 o = sh_se[n2];
                const float l2 = pt - o.x;
                const float r2 = o.y - pt;
                const float m2 = fmaxf(l2, r2);
                if ((fminf(l2, r2) >= 0.0f) & (m2 >= lo) & (m2 < hi)) valid = false;
            }

            // GIoU epilogue (rcp; validated absmax 0 vs 3.9e-2 threshold).
            const float inv = invk[k];
            const float2 g = gk[k];
            const float b0 = pt - lk[k] * inv;
            const float b1 = pt + rk[k] * inv;
            const float inter = fmaxf(fminf(b1, g.y) - fmaxf(b0, g.x), 0.0f);
            const float uni = (b1 - b0) + (g.y - g.x) - inter;
            const float iou = inter * __builtin_amdgcn_rcpf(uni + EPS_F);
            const float enc = fmaxf(b1, g.y) - fminf(b0, g.x);
            float giou = iou - (enc - uni) * __builtin_amdgcn_rcpf(enc + EPS_F);
            giou = fminf(fmaxf(giou, -1.0f), 1.0f);
            loss_sum += valid ? (1.0f - giou) : 0.0f;
            pos_sum  += valid ? 1.0f : 0.0f;
        }
    }

    // Wave reduce, cross-wave via LDS, final division in-block.
    for (int o = 32; o > 0; o >>= 1) {
        loss_sum += __shfl_down(loss_sum, o, 64);
        pos_sum  += __shfl_down(pos_sum,  o, 64);
    }
    if (lane == 0) { red_l[wave] = loss_sum; red_p[wave] = pos_sum; }
    __syncthreads();
    if (t < 16) {
        float Ls = red_l[t];
        float Ps = red_p[t];
#pragma unroll
        for (int o = 8; o > 0; o >>= 1) {
            Ls += __shfl_down(Ls, o, 16);
            Ps += __shfl_down(Ps, o, 16);
        }
        if (t == 0) out[b] = Ls / fmaxf(Ps, 1.0f);
    }
}

extern "C" void kernel_launch(void* const* d_in, const int* in_sizes, int n_in,
                              void* d_out, int out_size, void* d_ws, size_t ws_size,
                              hipStream_t stream) {
    const float* reg = (const float*)d_in[0];
    const float* ann = (const float*)d_in[1];
    // d_in[2] = class_id (unused); anchors d_in[3..8] are analytic, not read.
    const int c0 = in_sizes[3];
    const int A = in_sizes[3] + in_sizes[4] + in_sizes[5] +
                  in_sizes[6] + in_sizes[7] + in_sizes[8];
    const int B = out_size;                  // 4
    (void)d_ws; (void)ws_size;

    rl_lean<<<dim3(B), TPB, 0, stream>>>(reg, ann, c0, A, (float*)d_out);
}

// Round 9
// 73.879 us; speedup vs baseline: 1.1291x; 1.0446x over previous
//
#include <hip/hip_runtime.h>

#define EPS_F 1e-7f
#define NN 32        // N fixed at 32 by the problem setup
#define MARGIN 3     // conservative range margin (anchor units); fp slop ≤ 0.05
#define NSEG (NN * 6)
#define TPB 1024     // 16 waves: 4/SIMD for latency hiding
#define CHUNK 4      // software-pipeline factor for the candidate loop
#define CAND_MAX 24576  // provable worst-case T ~19k + slack

// rl_fused v9 == v6 (verified best: 74.0 µs total, absmax 0.0). Reverted
// after v7 (CU-spreading, +9.4 µs: serialized cross-block atomic handoff +
// extra graph node) and v8 (per-gt lean setup, +3.2 µs: load imbalance +
// coarser overlap mask) both regressed. Session ladder:
//   v2 82.7 -> v4 76.5 -> v6 74.0 | v5 111 (coop launch) v7 83.4 v8 77.2
// Structure: flat prefix-summed candidate list (load-balanced), CHUNK=4
// software-pipelined decode+load (phase 1 issues 4 independent LDS+HBM
// chains, phase 2 computes from registers), per-segment overlap mask with
// ctz first-match, shfl-broadcast segmask build, wave-0 shfl scan.
// Range derivation, exact fp32 predicate, first-match semantics and
// rcp-GIoU bit-identical to the reference-verified kernel.
__global__ __launch_bounds__(TPB) void rl_fused(
    const float* __restrict__ reg,   // (B, A, 2)
    const float* __restrict__ ann,   // (B, N, 3)
    int c0, int A,
    float* __restrict__ out)         // (B,) final loss per sample
{
    const int b = blockIdx.x;
    const int t = threadIdx.x;
    const int wave = t >> 6;
    const int lane = t & 63;

    __shared__ float2 sh_se[NN];       // sorted (s,e), ascending length
    __shared__ int4   seg[NSEG];       // {l0, r0, lenL|(lenR<<16), start<<16|n<<8|lvl}
    __shared__ int    pfx[NSEG];       // counts, then inclusive prefix
    __shared__ unsigned segmask[NSEG]; // earlier-gt overlap mask per segment
    __shared__ unsigned cand32[CAND_MAX / 4];  // flat candidate -> segment id
    __shared__ float  sh_sz[8];
    __shared__ float  red_l[TPB / 64], red_p[TPB / 64];

    // SIZES as double-exprs cast to f32 — JAX weak-scalar promotion.
    if (t < 8) {
        const float szc[8] = {
            0.0f,
            (float)(2.23147392 * (22050.0 / 256.0)),
            (float)(2.62519274 * (22050.0 / 256.0)),
            (float)(3.74199546 * (22050.0 / 256.0)),
            (float)(5.78800454 * (22050.0 / 256.0)),
            (float)(8.02371882 * (22050.0 / 256.0)),
            __builtin_inff(), __builtin_inff()
        };
        sh_sz[t] = szc[t];
    }

    // Shfl-based stable rank sort by length (wave 0, lanes 0..31 only) —
    // identical to the verified kernel.
    if (t < NN) {
        const float* an = ann + (size_t)b * (size_t)NN * 3;
        const float s0 = an[t * 3 + 0];
        const float e0 = an[t * 3 + 1];
        const float len = e0 - s0;
        int rank = 0;
#pragma unroll
        for (int j = 0; j < NN; ++j) {
            const float lj = __shfl(len, j, 64);
            rank += (lj < len) || (lj == len && j < t);
        }
        sh_se[rank] = make_float2(s0, e0);
    }
    __syncthreads();

    // Every lane caches sorted gt (s,e) for lane&31 -> 2 VGPR; the segmask
    // overlap test below reads it via __shfl (VALU, no LDS latency).
    float tsx, tsy;
    {
        const float2 tmp = sh_se[lane & 31];
        tsx = tmp.x; tsy = tmp.y;
    }

    // Per-(gt,lvl) conservative ranges — verified MARGIN superset logic —
    // plus the earlier-gt overlap mask. t<192 = waves 0..2 fully active.
    if (t < NSEG) {
        const int n   = t / 6;
        const int lvl = t - n * 6;
        const float2 se = sh_se[n];
        const float s = se.x, e = se.y;
        const float mid   = 0.5f * (s + e);
        const float halfL = 0.5f * (e - s);
        const float lo = sh_sz[lvl];
        const float hi = sh_sz[lvl + 1];
        const int   cnt = c0 >> lvl;
        const float inv   = __int_as_float((127 - lvl) << 23);  // 2^-lvl
        const float scale = __int_as_float((127 + lvl) << 23);  // 2^lvl

        // m(pt) = L/2 + |pt - mid|; band => |pt-mid| in [dlo, dhi).
        const float dlo = fmaxf(lo - halfL, 0.0f);
        const float dhi = hi - halfL;                // +inf at lvl 5 is fine
        const float prl = fmaxf(mid + dlo, s);       // right interval
        const float prh = fminf(mid + dhi, e);
        const float pll = fmaxf(mid - dhi, s);       // left interval
        const float plh = fminf(mid - dlo, e);

        int r0 = (int)floorf(prl * inv - 0.5f) - MARGIN;
        int r1 = (int)floorf(prh * inv - 0.5f) + MARGIN;
        int l0 = (int)floorf(pll * inv - 0.5f) - MARGIN;
        int l1 = (int)floorf(plh * inv - 0.5f) + MARGIN;
        r0 = max(r0, 0); r1 = min(r1, cnt - 1);
        l0 = max(l0, 0); l1 = min(l1, cnt - 1);
        if (r1 >= r0) l1 = min(l1, r0 - 1);          // disjoint union
        const int lenL = max(l1 - l0 + 1, 0);
        const int lenR = max(r1 - r0 + 1, 0);
        seg[t] = make_int4(l0, r0, lenL | (lenR << 16), (n << 8) | lvl);
        pfx[t] = lenL + lenR;

        // Anchor-pt span of this segment (same fp expr as the j-loop's pt,
        // so the span test is an exact superset of the in_gt condition).
        const int firstloc = lenL ? l0 : r0;
        const int lastloc  = lenR ? r1 : l1;
        const float ptmin = ((float)firstloc + 0.5f) * scale;
        const float ptmax = ((float)lastloc  + 0.5f) * scale;
        unsigned msk = 0u;
#pragma unroll
        for (int n2 = 0; n2 < NN - 1; ++n2) {
            const float ox = __shfl(tsx, n2, 64);    // uniform: waves 0-2 full
            const float oy = __shfl(tsy, n2, 64);
            msk |= ((n2 < n) & (ox <= ptmax) & (oy >= ptmin)) ? (1u << n2) : 0u;
        }
        segmask[t] = msk;
    }
    __syncthreads();

    // Wave-0 shfl inclusive scan over the 192 counts (3 chunks of 64).
    if (wave == 0) {
        int carry = 0;
#pragma unroll
        for (int k = 0; k < 3; ++k) {
            int v = pfx[k * 64 + lane];
#pragma unroll
            for (int o = 1; o < 64; o <<= 1) {
                const int u = __shfl_up(v, o, 64);
                v += (lane >= o) ? u : 0;
            }
            pfx[k * 64 + lane] = v + carry;
            carry += __shfl(v, 63, 64);   // chunk total, broadcast
        }
    }
    __syncthreads();
    const int T = min(pfx[NSEG - 1], CAND_MAX);   // clamp provably inactive

    // Fill the flat candidate->segment byte map (u32-packed); pack start
    // into seg.w high 16 bits (start < 24576 < 2^16).
    if (t < NSEG) {
        const int4 sg = seg[t];
        const int count = (sg.z & 0xffff) + (sg.z >> 16);
        const int start = pfx[t] - count;
        seg[t].w = sg.w | (start << 16);
        unsigned char* cbw = (unsigned char*)cand32;
        int i = start;
        const int end = min(start + count, CAND_MAX);
        const unsigned rep = 0x01010101u * (unsigned)t;
        while (i < end && (i & 3)) cbw[i++] = (unsigned char)t;
        for (; i + 4 <= end; i += 4) cand32[i >> 2] = rep;
        for (; i < end; ++i) cbw[i] = (unsigned char)t;
    }
    __syncthreads();

    const int twoc0 = 2 * c0;
    const unsigned char* cb = (const unsigned char*)cand32;
    const float2* reg2 = (const float2*)reg + (size_t)b * A;
    float loss_sum = 0.0f, pos_sum = 0.0f;

    for (int jb = t; jb < T; jb += TPB * CHUNK) {
        // ---- phase 1: decode + issue all CHUNK independent load chains ----
        float2 gk[CHUNK];
        float  ptk[CHUNK], lk[CHUNK], rk[CHUNK], lok[CHUNK], hik[CHUNK], invk[CHUNK];
        unsigned mskk[CHUNK];
        bool validk[CHUNK];
#pragma unroll
        for (int k = 0; k < CHUNK; ++k) {
            const int j = jb + k * TPB;
            const bool act = j < T;
            const int jj = act ? j : 0;              // clamp to a real candidate
            const int sid = cb[jj];                  // 1 LDS byte read
            const int4 sg = seg[sid];                // 1 ds_read_b128
            mskk[k] = segmask[sid];                  // independent b32 read
            const int lenL  = sg.z & 0xffff;
            const int start = (int)(((unsigned)sg.w) >> 16);
            const int n     = (sg.w >> 8) & 0xff;
            const int lvl   = sg.w & 0xff;
            const int local = jj - start;
            const int loc = (local < lenL) ? (sg.x + local) : (sg.y + (local - lenL));
            const float scale = __int_as_float((127 + lvl) << 23);  // 2^lvl
            invk[k] = __int_as_float((127 - lvl) << 23);            // 2^-lvl
            const int aoff = twoc0 - (twoc0 >> lvl);

            // Global load issued here — independent across k, all in flight.
            gk[k] = reg2[aoff + loc];

            const float pt = ((float)loc + 0.5f) * scale;  // bit-exact anchor
            ptk[k] = pt;
            lok[k] = sh_sz[lvl];
            hik[k] = sh_sz[lvl + 1];
            const float2 se = sh_se[n];
            const float l = pt - se.x;
            const float r = se.y - pt;
            lk[k] = l; rk[k] = r;
            const float m = fmaxf(l, r);
            // EXACT reference predicate (fp32, same op order/compares).
            validk[k] = act & (fminf(l, r) >= 0.0f) & (m >= lok[k]) & (m < hik[k]);
        }

        // ---- phase 2: first-match + GIoU from registers ----
#pragma unroll
        for (int k = 0; k < CHUNK; ++k) {
            bool valid = validk[k];
            unsigned msk = mskk[k];
            const float pt = ptk[k];
            const float lo = lok[k], hi = hik[k];
            // First-match via overlap mask: exact predicate only on the
            // (rare) earlier gts whose [s,e] intersects the anchor span.
            while (valid && msk) {
                const int n2 = __builtin_ctz(msk);
                msk &= msk - 1u;
                const float2 o = sh_se[n2];
                const float l2 = pt - o.x;
                const float r2 = o.y - pt;
                const float m2 = fmaxf(l2, r2);
                if ((fminf(l2, r2) >= 0.0f) & (m2 >= lo) & (m2 < hi)) valid = false;
            }

            // GIoU epilogue (rcp; validated absmax 0 vs 3.9e-2 threshold).
            const float inv = invk[k];
            const float2 g = gk[k];
            const float b0 = pt - lk[k] * inv;
            const float b1 = pt + rk[k] * inv;
            const float inter = fmaxf(fminf(b1, g.y) - fmaxf(b0, g.x), 0.0f);
            const float uni = (b1 - b0) + (g.y - g.x) - inter;
            const float iou = inter * __builtin_amdgcn_rcpf(uni + EPS_F);
            const float enc = fmaxf(b1, g.y) - fminf(b0, g.x);
            float giou = iou - (enc - uni) * __builtin_amdgcn_rcpf(enc + EPS_F);
            giou = fminf(fmaxf(giou, -1.0f), 1.0f);
            loss_sum += valid ? (1.0f - giou) : 0.0f;
            pos_sum  += valid ? 1.0f : 0.0f;
        }
    }

    // Wave reduce, cross-wave via LDS, final division in-block.
    for (int o = 32; o > 0; o >>= 1) {
        loss_sum += __shfl_down(loss_sum, o, 64);
        pos_sum  += __shfl_down(pos_sum,  o, 64);
    }
    if (lane == 0) { red_l[wave] = loss_sum; red_p[wave] = pos_sum; }
    __syncthreads();
    if (t < 16) {
        float Ls = red_l[t];
        float Ps = red_p[t];
#pragma unroll
        for (int o = 8; o > 0; o >>= 1) {
            Ls += __shfl_down(Ls, o, 16);
            Ps += __shfl_down(Ps, o, 16);
        }
        if (t == 0) out[b] = Ls / fmaxf(Ps, 1.0f);
    }
}

extern "C" void kernel_launch(void* const* d_in, const int* in_sizes, int n_in,
                              void* d_out, int out_size, void* d_ws, size_t ws_size,
                              hipStream_t stream) {
    const float* reg = (const float*)d_in[0];
    const float* ann = (const float*)d_in[1];
    // d_in[2] = class_id (unused); anchors d_in[3..8] are analytic, not read.
    const int c0 = in_sizes[3];
    const int A = in_sizes[3] + in_sizes[4] + in_sizes[5] +
                  in_sizes[6] + in_sizes[7] + in_sizes[8];
    const int B = out_size;                  // 4
    (void)d_ws; (void)ws_size;

    rl_fused<<<dim3(B), TPB, 0, stream>>>(reg, ann, c0, A, (float*)d_out);
}